// Round 2
// baseline (250.036 us; speedup 1.0000x reference)
//
#include <hip/hip_runtime.h>
#include <hip/hip_bf16.h>

// CBFHalfspace: h(x)=b-Ax with A[:,0:2]=[[-1,0],[1,0],[0,-1],[0,1]], b=[1,1,1,1].
// h is affine and A's column sums are zero => grad(sum h) == 0 identically, so
// Lfh = Lf2h = LgLfh = 0 exactly. Per-row output (8 floats):
//   [1+x0, 1-x0, 1+x1, 1-x1, 0, 0, 0, 0]
//
// Memory-bound: read B*7 f32 (117 MB; every 64B line of x contains needed
// bytes since rows are 28 B), write B*8 f32 (134 MB). Roofline ~40 us.
//
// Store layout: out viewed as 2B float4 slots; even slot k holds h(row k/2),
// odd slot holds zeros. One thread per slot => consecutive lanes store
// consecutive float4s => full-line (64 B) store transactions, no partial-line
// RFO traffic. Lane pairs (2m, 2m+1) load the same x row => loads broadcast,
// line footprint unchanged.

__global__ __launch_bounds__(256) void CBFHalfspace_68917045231689_kernel(
        const float* __restrict__ x, float4* __restrict__ out4, int n4) {
    int k = blockIdx.x * blockDim.x + threadIdx.x;
    if (k >= n4) return;

    int row = k >> 1;               // row*7+1 max = 29,360,129 — fits int32
    const float x0 = x[row * 7 + 0];
    const float x1 = x[row * 7 + 1];

    float4 h = make_float4(1.0f + x0, 1.0f - x0, 1.0f + x1, 1.0f - x1);
    float4 z = make_float4(0.0f, 0.0f, 0.0f, 0.0f);

    out4[k] = (k & 1) ? z : h;
}

extern "C" void kernel_launch(void* const* d_in, const int* in_sizes, int n_in,
                              void* d_out, int out_size, void* d_ws, size_t ws_size,
                              hipStream_t stream) {
    const float* x = (const float*)d_in[0];
    // d_in[1] (f) and d_in[2] (g) are mathematically irrelevant: grad(sum h)=0.
    float4* out4 = (float4*)d_out;

    const int B = in_sizes[0] / 7;
    const int n4 = B * 2;           // 8,388,608 float4 slots
    const int block = 256;
    const int grid = (n4 + block - 1) / block;
    CBFHalfspace_68917045231689_kernel<<<grid, block, 0, stream>>>(x, out4, n4);
}

// Round 4
// 220.818 us; speedup vs baseline: 1.1323x; 1.1323x over previous
//
#include <hip/hip_runtime.h>
#include <hip/hip_bf16.h>

// CBFHalfspace: h(x)=b-Ax with A[:,0:2]=[[-1,0],[1,0],[0,-1],[0,1]], b=[1,1,1,1].
// h is affine, A's column sums are zero => grad(sum h)==0 identically, so
// Lfh = Lf2h = LgLfh = 0 exactly. Per-row output (8 floats):
//   [1+x0, 1-x0, 1+x1, 1-x1, 0, 0, 0, 0]
//
// Ideal traffic: read 117 MB of x, write 134 MB of out.
// Round-2 rocprof showed WRITE_SIZE ~375 MB: the harness's 0xAA poison fill
// (~537 MB, 2x the 256 MB L3) leaves L3 full of dirty poison; normal
// (allocating) stores force ~250 MB of poison evictions inside OUR dispatch.
// Fix: __builtin_nontemporal_store (gfx950 `nt`) streams the output to HBM
// without allocating, so we stop paying for poison evictions. Loads stay
// regular (x partially hits L3 from the harness restore copy: FETCH 65 MB).
//
// NT stores must cover full 64B lines per instruction -> stage h in LDS,
// then unit-stride float4 NT stores (even slot = h row, odd slot = zeros).
// NOTE: __builtin_nontemporal_store rejects HIP_vector_type float4 — use a
// Clang native ext_vector_type instead.

typedef float v4f __attribute__((ext_vector_type(4)));

__global__ __launch_bounds__(256) void CBFHalfspace_68917045231689_kernel(
        const float* __restrict__ x, v4f* __restrict__ out4, int B) {
    __shared__ v4f hbuf[256];

    const int t = threadIdx.x;
    const int row = blockIdx.x * 256 + t;
    if (row < B) {
        // Row is 7 floats; only x0,x1 needed. row*7+1 <= 29,360,129 (int32 ok).
        const float x0 = x[row * 7 + 0];
        const float x1 = x[row * 7 + 1];
        hbuf[t] = (v4f){1.0f + x0, 1.0f - x0, 1.0f + x1, 1.0f - x1};
    }
    __syncthreads();

    const v4f z = (v4f){0.0f, 0.0f, 0.0f, 0.0f};
    // Block owns 512 consecutive float4 slots: slot s even -> h(row s/2), odd -> 0.
    const size_t base = (size_t)blockIdx.x * 512;

    // slot s = t  (rows 0..127 of this block)
    v4f v0 = (t & 1) ? z : hbuf[t >> 1];
    __builtin_nontemporal_store(v0, &out4[base + t]);

    // slot s = t + 256  (rows 128..255; parity of s == parity of t)
    v4f v1 = (t & 1) ? z : hbuf[(t >> 1) + 128];
    __builtin_nontemporal_store(v1, &out4[base + t + 256]);
}

extern "C" void kernel_launch(void* const* d_in, const int* in_sizes, int n_in,
                              void* d_out, int out_size, void* d_ws, size_t ws_size,
                              hipStream_t stream) {
    const float* x = (const float*)d_in[0];
    // d_in[1] (f) and d_in[2] (g) are mathematically irrelevant: grad(sum h)=0.
    v4f* out4 = (v4f*)d_out;

    const int B = in_sizes[0] / 7;       // 4,194,304 rows
    const int block = 256;
    const int grid = (B + block - 1) / block;  // 16384 blocks, B % 256 == 0
    CBFHalfspace_68917045231689_kernel<<<grid, block, 0, stream>>>(x, out4, B);
}